// Round 1
// baseline (426.263 us; speedup 1.0000x reference)
//
#include <hip/hip_runtime.h>

// Problem constants (fixed by the reference)
#define NG    4096        // graphs
#define NPG   198         // nodes per graph
#define EPG   1584        // edges per graph (E/G = 8*198)
#define ETOT  (NG * EPG)  // total edges = 6488064

// ---------------------------------------------------------------------------
// Conv kernel: one block per graph. Builds CSR-by-dst in LDS (counting sort),
// then runs all 5 GraphConv layers with node-per-thread gather (no atomics in
// the inner loops). Writes the flattened [G,396] feature to workspace H.
// ---------------------------------------------------------------------------

template <int CIN, int COUT>
__device__ __forceinline__ void conv_layer(
    const float* h_in, float* h_out,
    const unsigned short* s_src, const float* s_ew,
    const unsigned* row_start,
    const float* __restrict__ wrel, const float* __restrict__ brel,
    const float* __restrict__ wroot, int tid)
{
    if (tid < NPG) {
        float agg[CIN], hi[CIN];
#pragma unroll
        for (int c = 0; c < CIN; ++c) { agg[c] = 0.f; hi[c] = h_in[tid * CIN + c]; }
        const unsigned jb = row_start[tid], je = row_start[tid + 1];
        for (unsigned j = jb; j < je; ++j) {
            const int   s = s_src[j];
            const float w = s_ew[j];
#pragma unroll
            for (int c = 0; c < CIN; ++c)
                agg[c] = fmaf(h_in[s * CIN + c], w, agg[c]);
        }
#pragma unroll
        for (int o = 0; o < COUT; ++o) {
            float acc = brel[o];
#pragma unroll
            for (int c = 0; c < CIN; ++c) {
                acc = fmaf(agg[c], wrel[o * CIN + c], acc);
                acc = fmaf(hi[c],  wroot[o * CIN + c], acc);
            }
            h_out[tid * COUT + o] = fmaxf(acc, 0.f);
        }
    }
}

__global__ __launch_bounds__(256) void conv_kernel(
    const float* __restrict__ x,
    const int*   __restrict__ eidx,   // [2, ETOT]
    const float* __restrict__ ew,     // [ETOT]
    const float* wr0, const float* br0, const float* wq0,
    const float* wr1, const float* br1, const float* wq1,
    const float* wr2, const float* br2, const float* wq2,
    const float* wr3, const float* br3, const float* wq3,
    const float* wr4, const float* br4, const float* wq4,
    float* __restrict__ Hout)         // [NG, 396]
{
    __shared__ unsigned short s_src[EPG];
    __shared__ float          s_ew[EPG];
    __shared__ unsigned       cnt[256];
    __shared__ unsigned       pscan[256];
    __shared__ unsigned       row_start[NPG + 1];
    __shared__ unsigned       cursor[NPG];
    __shared__ float          hA[NPG * 20];
    __shared__ float          hB[NPG * 20];

    const int g    = blockIdx.x;
    const int tid  = threadIdx.x;
    const int ebase = g * EPG;
    const int nbase = g * NPG;

    // --- pass 1: per-destination counts -----------------------------------
    cnt[tid] = 0u;
    __syncthreads();
    for (int e = tid; e < EPG; e += 256) {
        const int d = eidx[ETOT + ebase + e] - nbase;
        atomicAdd(&cnt[d], 1u);
    }
    __syncthreads();

    // --- inclusive Hillis-Steele scan over 256 slots ----------------------
    pscan[tid] = cnt[tid];
    for (int st = 1; st < 256; st <<= 1) {
        __syncthreads();
        const unsigned v = (tid >= st) ? pscan[tid - st] : 0u;
        __syncthreads();
        pscan[tid] += v;
    }
    __syncthreads();
    if (tid < NPG) {
        const unsigned rs = pscan[tid] - cnt[tid];   // exclusive
        row_start[tid] = rs;
        cursor[tid]    = rs;
    }
    if (tid == 0) row_start[NPG] = EPG;
    __syncthreads();

    // --- pass 2: place edges sorted by destination ------------------------
    for (int e = tid; e < EPG; e += 256) {
        const int   s = eidx[ebase + e] - nbase;
        const int   d = eidx[ETOT + ebase + e] - nbase;
        const float w = ew[ebase + e];
        const unsigned slot = atomicAdd(&cursor[d], 1u);
        s_src[slot] = (unsigned short)s;
        s_ew[slot]  = w;
    }
    // --- load x (198x2) ----------------------------------------------------
    for (int t = tid; t < NPG * 2; t += 256)
        hA[t] = x[nbase * 2 + t];
    __syncthreads();

    conv_layer<2, 20>(hA, hB, s_src, s_ew, row_start, wr0, br0, wq0, tid);
    __syncthreads();
    conv_layer<20, 15>(hB, hA, s_src, s_ew, row_start, wr1, br1, wq1, tid);
    __syncthreads();
    conv_layer<15, 10>(hA, hB, s_src, s_ew, row_start, wr2, br2, wq2, tid);
    __syncthreads();
    conv_layer<10, 5>(hB, hA, s_src, s_ew, row_start, wr3, br3, wq3, tid);
    __syncthreads();
    conv_layer<5, 2>(hA, hB, s_src, s_ew, row_start, wr4, br4, wq4, tid);
    __syncthreads();

    for (int t = tid; t < NPG * 2; t += 256)
        Hout[g * (NPG * 2) + t] = hB[t];
}

// ---------------------------------------------------------------------------
// MLP kernel: 16 graphs per block (256 blocks). Weights are L2-resident and
// amortized over 16 graphs. Ends with 2-class softmax.
// ---------------------------------------------------------------------------

template <int K, int M, bool RELU>
__device__ __forceinline__ void mlp_layer(
    const float* in, float* out,
    const float* __restrict__ w, const float* __restrict__ b, int tid)
{
    for (int t = tid; t < 16 * M; t += 256) {
        const int gg = t & 15;
        const int o  = t >> 4;
        float acc = b[o];
#pragma unroll 4
        for (int k = 0; k < K; ++k)
            acc = fmaf(w[o * K + k], in[gg * K + k], acc);
        out[gg * M + o] = RELU ? fmaxf(acc, 0.f) : acc;
    }
}

__global__ __launch_bounds__(256) void mlp_kernel(
    const float* __restrict__ H,      // [NG, 396]
    const float* lw0, const float* lb0,
    const float* lw1, const float* lb1,
    const float* lw2, const float* lb2,
    const float* lw3, const float* lb3,
    const float* lw4, const float* lb4,
    float* __restrict__ out)          // [NG, 2]
{
    __shared__ float bufA[16 * 396];
    __shared__ float bufB[16 * 200];

    const int tid  = threadIdx.x;
    const int base = blockIdx.x * 16 * 396;

    for (int t = tid; t < 16 * 396; t += 256)
        bufA[t] = H[base + t];
    __syncthreads();

    mlp_layer<396, 200, true>(bufA, bufB, lw0, lb0, tid);
    __syncthreads();
    mlp_layer<200, 100, true>(bufB, bufA, lw1, lb1, tid);
    __syncthreads();
    mlp_layer<100, 50, true>(bufA, bufB, lw2, lb2, tid);
    __syncthreads();
    mlp_layer<50, 10, true>(bufB, bufA, lw3, lb3, tid);
    __syncthreads();
    mlp_layer<10, 2, false>(bufA, bufB, lw4, lb4, tid);
    __syncthreads();

    if (tid < 16) {
        const int gg = blockIdx.x * 16 + tid;
        const float l0 = bufB[tid * 2], l1 = bufB[tid * 2 + 1];
        const float m  = fmaxf(l0, l1);
        const float e0 = __expf(l0 - m), e1 = __expf(l1 - m);
        const float inv = 1.f / (e0 + e1);
        out[gg * 2]     = e0 * inv;
        out[gg * 2 + 1] = e1 * inv;
    }
}

extern "C" void kernel_launch(void* const* d_in, const int* in_sizes, int n_in,
                              void* d_out, int out_size, void* d_ws, size_t ws_size,
                              hipStream_t stream)
{
    const float* x    = (const float*)d_in[0];
    const int*   eidx = (const int*)  d_in[1];
    const float* ew   = (const float*)d_in[2];

    const float* wr[5]; const float* br[5]; const float* wq[5];
    for (int i = 0; i < 5; ++i) {
        wr[i] = (const float*)d_in[3 + 3 * i];
        br[i] = (const float*)d_in[4 + 3 * i];
        wq[i] = (const float*)d_in[5 + 3 * i];
    }
    const float* lw[5]; const float* lb[5];
    for (int i = 0; i < 5; ++i) {
        lw[i] = (const float*)d_in[18 + 2 * i];
        lb[i] = (const float*)d_in[19 + 2 * i];
    }

    float* H = (float*)d_ws;   // [NG, 396] = 6.5 MB

    conv_kernel<<<NG, 256, 0, stream>>>(
        x, eidx, ew,
        wr[0], br[0], wq[0],
        wr[1], br[1], wq[1],
        wr[2], br[2], wq[2],
        wr[3], br[3], wq[3],
        wr[4], br[4], wq[4],
        H);

    mlp_kernel<<<NG / 16, 256, 0, stream>>>(
        H,
        lw[0], lb[0], lw[1], lb[1], lw[2], lb[2],
        lw[3], lb[3], lw[4], lb[4],
        (float*)d_out);
}

// Round 2
// 208.387 us; speedup vs baseline: 2.0455x; 2.0455x over previous
//
#include <hip/hip_runtime.h>

// Problem constants (fixed by the reference)
#define NG    4096        // graphs
#define NPG   198         // nodes per graph
#define EPG   1584        // edges per graph (E/G = 8*198)
#define ETOT  (NG * EPG)  // total edges = 6488064
#define GPB   8           // graphs per MLP block

// Workspace layout (floats):
//   HT   [NG/GPB][396][GPB]   = 1,622,016 floats (conv output, tile-transposed)
//   WT0..WT4 (transposed MLP weights, [K][M])
#define HT_FLOATS (NG / GPB * 396 * GPB)
#define WT0_OFF   (HT_FLOATS)
#define WT1_OFF   (WT0_OFF + 396 * 200)
#define WT2_OFF   (WT1_OFF + 200 * 100)
#define WT3_OFF   (WT2_OFF + 100 * 50)
#define WT4_OFF   (WT3_OFF + 50 * 10)

// ---------------------------------------------------------------------------
// Weight transpose: WT[k*M+o] = W[o*K+k], all 5 layers in one kernel.
// ---------------------------------------------------------------------------
__global__ __launch_bounds__(256) void wtrans_kernel(
    const float* __restrict__ w0, const float* __restrict__ w1,
    const float* __restrict__ w2, const float* __restrict__ w3,
    const float* __restrict__ w4, float* __restrict__ ws)
{
    const int b = blockIdx.x;
    const float* w; float* t; int K, M, nelem, base;
    if      (b < 310) { w = w0; t = ws + WT0_OFF; K = 396; M = 200; nelem = 79200; base = 0;   }
    else if (b < 389) { w = w1; t = ws + WT1_OFF; K = 200; M = 100; nelem = 20000; base = 310; }
    else if (b < 409) { w = w2; t = ws + WT2_OFF; K = 100; M = 50;  nelem = 5000;  base = 389; }
    else if (b < 411) { w = w3; t = ws + WT3_OFF; K = 50;  M = 10;  nelem = 500;   base = 409; }
    else              { w = w4; t = ws + WT4_OFF; K = 10;  M = 2;   nelem = 20;    base = 411; }
    const int e = (b - base) * 256 + threadIdx.x;
    if (e < nelem) {
        const int o = e / K, k = e - o * K;
        t[k * M + o] = w[e];
    }
}

// ---------------------------------------------------------------------------
// Conv kernel: one block per graph. CSR-by-dst in LDS (counting sort), then
// 5 fused GraphConv layers. Output written tile-transposed: HT[b][k][g&7].
// ---------------------------------------------------------------------------

template <int CIN, int COUT>
__device__ __forceinline__ void conv_layer(
    const float* h_in, float* h_out,
    const unsigned short* s_src, const float* s_ew,
    const unsigned* row_start,
    const float* __restrict__ wrel, const float* __restrict__ brel,
    const float* __restrict__ wroot, int tid)
{
    if (tid < NPG) {
        float agg[CIN], hi[CIN];
#pragma unroll
        for (int c = 0; c < CIN; ++c) { agg[c] = 0.f; hi[c] = h_in[tid * CIN + c]; }
        const unsigned jb = row_start[tid], je = row_start[tid + 1];
        for (unsigned j = jb; j < je; ++j) {
            const int   s = s_src[j];
            const float w = s_ew[j];
#pragma unroll
            for (int c = 0; c < CIN; ++c)
                agg[c] = fmaf(h_in[s * CIN + c], w, agg[c]);
        }
#pragma unroll
        for (int o = 0; o < COUT; ++o) {
            float acc = brel[o];
#pragma unroll
            for (int c = 0; c < CIN; ++c) {
                acc = fmaf(agg[c], wrel[o * CIN + c], acc);
                acc = fmaf(hi[c],  wroot[o * CIN + c], acc);
            }
            h_out[tid * COUT + o] = fmaxf(acc, 0.f);
        }
    }
}

__global__ __launch_bounds__(256) void conv_kernel(
    const float* __restrict__ x,
    const int*   __restrict__ eidx,   // [2, ETOT]
    const float* __restrict__ ew,     // [ETOT]
    const float* wr0, const float* br0, const float* wq0,
    const float* wr1, const float* br1, const float* wq1,
    const float* wr2, const float* br2, const float* wq2,
    const float* wr3, const float* br3, const float* wq3,
    const float* wr4, const float* br4, const float* wq4,
    float* __restrict__ HT)           // tile-transposed [NG/8][396][8]
{
    __shared__ unsigned short s_src[EPG];
    __shared__ float          s_ew[EPG];
    __shared__ unsigned       cnt[256];
    __shared__ unsigned       pscan[256];
    __shared__ unsigned       row_start[NPG + 1];
    __shared__ unsigned       cursor[NPG];
    __shared__ float          hA[NPG * 20];
    __shared__ float          hB[NPG * 20];

    const int g    = blockIdx.x;
    const int tid  = threadIdx.x;
    const int ebase = g * EPG;
    const int nbase = g * NPG;

    // --- pass 1: per-destination counts -----------------------------------
    cnt[tid] = 0u;
    __syncthreads();
    for (int e = tid; e < EPG; e += 256) {
        const int d = eidx[ETOT + ebase + e] - nbase;
        atomicAdd(&cnt[d], 1u);
    }
    __syncthreads();

    // --- inclusive Hillis-Steele scan over 256 slots ----------------------
    pscan[tid] = cnt[tid];
    for (int st = 1; st < 256; st <<= 1) {
        __syncthreads();
        const unsigned v = (tid >= st) ? pscan[tid - st] : 0u;
        __syncthreads();
        pscan[tid] += v;
    }
    __syncthreads();
    if (tid < NPG) {
        const unsigned rs = pscan[tid] - cnt[tid];   // exclusive
        row_start[tid] = rs;
        cursor[tid]    = rs;
    }
    if (tid == 0) row_start[NPG] = EPG;
    __syncthreads();

    // --- pass 2: place edges sorted by destination ------------------------
    for (int e = tid; e < EPG; e += 256) {
        const int   s = eidx[ebase + e] - nbase;
        const int   d = eidx[ETOT + ebase + e] - nbase;
        const float w = ew[ebase + e];
        const unsigned slot = atomicAdd(&cursor[d], 1u);
        s_src[slot] = (unsigned short)s;
        s_ew[slot]  = w;
    }
    // --- load x (198x2) ----------------------------------------------------
    for (int t = tid; t < NPG * 2; t += 256)
        hA[t] = x[nbase * 2 + t];
    __syncthreads();

    conv_layer<2, 20>(hA, hB, s_src, s_ew, row_start, wr0, br0, wq0, tid);
    __syncthreads();
    conv_layer<20, 15>(hB, hA, s_src, s_ew, row_start, wr1, br1, wq1, tid);
    __syncthreads();
    conv_layer<15, 10>(hA, hB, s_src, s_ew, row_start, wr2, br2, wq2, tid);
    __syncthreads();
    conv_layer<10, 5>(hB, hA, s_src, s_ew, row_start, wr3, br3, wq3, tid);
    __syncthreads();
    conv_layer<5, 2>(hA, hB, s_src, s_ew, row_start, wr4, br4, wq4, tid);
    __syncthreads();

    // --- store tile-transposed: HT[g>>3][t][g&7] ---------------------------
    float* ht = HT + (size_t)(g >> 3) * (396 * GPB);
    const int j = g & 7;
    for (int t = tid; t < 396; t += 256)
        ht[t * GPB + j] = hB[t];
}

// ---------------------------------------------------------------------------
// MLP kernel: 8 graphs per block (512 blocks). Thread = output neuron o,
// 8 accumulators (one per graph). Inputs at step k are wave-uniform 32B
// ([k][g] layout) -> scalar loads; weights are lane-coalesced (WT[k][o]).
// ---------------------------------------------------------------------------

template <int K, int M>
__device__ __forceinline__ void mlpT(
    const float* __restrict__ inT,    // [K][8], uniform across lanes
    float* __restrict__ outT,         // [M][8]
    const float* __restrict__ wt,     // [K][M] transposed weights
    const float* __restrict__ bias,   // [M]
    int tid, bool relu)
{
    if (tid < M) {
        float acc[GPB];
        const float b = bias[tid];
#pragma unroll
        for (int j = 0; j < GPB; ++j) acc[j] = b;
#pragma unroll 4
        for (int k = 0; k < K; ++k) {
            const float wv = wt[k * M + tid];
            const float4 i0 = *(const float4*)(inT + k * GPB);
            const float4 i1 = *(const float4*)(inT + k * GPB + 4);
            acc[0] = fmaf(wv, i0.x, acc[0]);
            acc[1] = fmaf(wv, i0.y, acc[1]);
            acc[2] = fmaf(wv, i0.z, acc[2]);
            acc[3] = fmaf(wv, i0.w, acc[3]);
            acc[4] = fmaf(wv, i1.x, acc[4]);
            acc[5] = fmaf(wv, i1.y, acc[5]);
            acc[6] = fmaf(wv, i1.z, acc[6]);
            acc[7] = fmaf(wv, i1.w, acc[7]);
        }
#pragma unroll
        for (int j = 0; j < GPB; ++j)
            outT[tid * GPB + j] = relu ? fmaxf(acc[j], 0.f) : acc[j];
    }
}

__global__ __launch_bounds__(256) void mlp_kernel(
    const float* __restrict__ HT,     // [NG/8][396][8]
    const float* __restrict__ ws,     // workspace base (for WT*)
    const float* __restrict__ lb0, const float* __restrict__ lb1,
    const float* __restrict__ lb2, const float* __restrict__ lb3,
    const float* __restrict__ lb4,
    float* __restrict__ out)          // [NG, 2]
{
    __shared__ __align__(16) float bufA[200 * GPB];
    __shared__ __align__(16) float bufB[100 * GPB];

    const int tid = threadIdx.x;
    const float* __restrict__ ht = HT + (size_t)blockIdx.x * (396 * GPB);

    mlpT<396, 200>(ht,   bufA, ws + WT0_OFF, lb0, tid, true);
    __syncthreads();
    mlpT<200, 100>(bufA, bufB, ws + WT1_OFF, lb1, tid, true);
    __syncthreads();
    mlpT<100, 50>(bufB,  bufA, ws + WT2_OFF, lb2, tid, true);
    __syncthreads();
    mlpT<50, 10>(bufA,   bufB, ws + WT3_OFF, lb3, tid, true);
    __syncthreads();

    // layer 4 (10 -> 2) + softmax, one thread per graph
    if (tid < GPB) {
        const int j = tid;
        const float* __restrict__ wt4 = ws + WT4_OFF;
        float l0 = lb4[0], l1 = lb4[1];
#pragma unroll
        for (int k = 0; k < 10; ++k) {
            const float v = bufB[k * GPB + j];
            l0 = fmaf(v, wt4[k * 2 + 0], l0);
            l1 = fmaf(v, wt4[k * 2 + 1], l1);
        }
        const float m  = fmaxf(l0, l1);
        const float e0 = __expf(l0 - m), e1 = __expf(l1 - m);
        const float inv = 1.f / (e0 + e1);
        float2 p; p.x = e0 * inv; p.y = e1 * inv;
        ((float2*)out)[blockIdx.x * GPB + j] = p;
    }
}

extern "C" void kernel_launch(void* const* d_in, const int* in_sizes, int n_in,
                              void* d_out, int out_size, void* d_ws, size_t ws_size,
                              hipStream_t stream)
{
    const float* x    = (const float*)d_in[0];
    const int*   eidx = (const int*)  d_in[1];
    const float* ew   = (const float*)d_in[2];

    const float* wr[5]; const float* br[5]; const float* wq[5];
    for (int i = 0; i < 5; ++i) {
        wr[i] = (const float*)d_in[3 + 3 * i];
        br[i] = (const float*)d_in[4 + 3 * i];
        wq[i] = (const float*)d_in[5 + 3 * i];
    }
    const float* lw[5]; const float* lb[5];
    for (int i = 0; i < 5; ++i) {
        lw[i] = (const float*)d_in[18 + 2 * i];
        lb[i] = (const float*)d_in[19 + 2 * i];
    }

    float* ws = (float*)d_ws;

    wtrans_kernel<<<412, 256, 0, stream>>>(lw[0], lw[1], lw[2], lw[3], lw[4], ws);

    conv_kernel<<<NG, 256, 0, stream>>>(
        x, eidx, ew,
        wr[0], br[0], wq[0],
        wr[1], br[1], wq[1],
        wr[2], br[2], wq[2],
        wr[3], br[3], wq[3],
        wr[4], br[4], wq[4],
        ws /* HT at offset 0 */);

    mlp_kernel<<<NG / GPB, 256, 0, stream>>>(
        ws /* HT */, ws /* WT base */,
        lb[0], lb[1], lb[2], lb[3], lb[4],
        (float*)d_out);
}

// Round 3
// 152.377 us; speedup vs baseline: 2.7974x; 1.3676x over previous
//
#include <hip/hip_runtime.h>
#include <hip/hip_fp16.h>

// Problem constants (fixed by the reference)
#define NG    4096        // graphs
#define NPG   198         // nodes per graph
#define EPG   1584        // edges per graph (E/G = 8*198)
#define ETOT  (NG * EPG)  // total edges = 6488064
#define GPB   8           // graphs per MLP block

// Workspace layout (floats):
#define HT_FLOATS (NG / GPB * 396 * GPB)
#define WT0_OFF   (HT_FLOATS)
#define WT1_OFF   (WT0_OFF + 396 * 200)
#define WT2_OFF   (WT1_OFF + 200 * 100)
#define WT3_OFF   (WT2_OFF + 100 * 50)
#define WT4_OFF   (WT3_OFF + 50 * 10)

// ---------------------------------------------------------------------------
// Weight transpose: WT[k*M+o] = W[o*K+k], all 5 MLP layers in one kernel.
// ---------------------------------------------------------------------------
__global__ __launch_bounds__(256) void wtrans_kernel(
    const float* __restrict__ w0, const float* __restrict__ w1,
    const float* __restrict__ w2, const float* __restrict__ w3,
    const float* __restrict__ w4, float* __restrict__ ws)
{
    const int b = blockIdx.x;
    const float* w; float* t; int K, M, nelem, base;
    if      (b < 310) { w = w0; t = ws + WT0_OFF; K = 396; M = 200; nelem = 79200; base = 0;   }
    else if (b < 389) { w = w1; t = ws + WT1_OFF; K = 200; M = 100; nelem = 20000; base = 310; }
    else if (b < 409) { w = w2; t = ws + WT2_OFF; K = 100; M = 50;  nelem = 5000;  base = 389; }
    else if (b < 411) { w = w3; t = ws + WT3_OFF; K = 50;  M = 10;  nelem = 500;   base = 409; }
    else              { w = w4; t = ws + WT4_OFF; K = 10;  M = 2;   nelem = 20;    base = 411; }
    const int e = (b - base) * 256 + threadIdx.x;
    if (e < nelem) {
        const int o = e / K, k = e - o * K;
        t[k * M + o] = w[e];
    }
}

// ---------------------------------------------------------------------------
// Conv layer: node-per-thread gather over CSR-by-dst edges. Node features
// live in LDS as half2-packed rows padded to 16B multiples -> b128 gathers.
// Aggregation in packed f16 (__hfma2); dense lin_rel/lin_root in fp32.
// ---------------------------------------------------------------------------
template <int CIN, int COUT, int RIN_W, int ROUT_W>
__device__ __forceinline__ void conv_layer_h(
    const unsigned* __restrict__ h_in,   // [NPG][RIN_W] half2 words
    unsigned* __restrict__ h_out,        // [NPG][ROUT_W]
    const unsigned* __restrict__ s_edge, // (half(w)<<16)|src
    const unsigned* __restrict__ row_start,
    const float* __restrict__ wrel, const float* __restrict__ brel,
    const float* __restrict__ wroot, int tid)
{
    if (tid >= NPG) return;

    __half2 agg2[RIN_W];
    const __half2 z2 = __floats2half2_rn(0.f, 0.f);
#pragma unroll
    for (int p = 0; p < RIN_W; ++p) agg2[p] = z2;

    const unsigned jb = row_start[tid], je = row_start[tid + 1];
    for (unsigned j = jb; j < je; ++j) {
        const unsigned e    = s_edge[j];
        const unsigned sidx = e & 0xFFFFu;
        const __half2  w2   = __builtin_bit_cast(__half2, (e >> 16) * 0x10001u);
        const unsigned* row = h_in + sidx * RIN_W;
        if constexpr (RIN_W == 1) {
            agg2[0] = __hfma2(w2, __builtin_bit_cast(__half2, row[0]), agg2[0]);
        } else {
#pragma unroll
            for (int ch = 0; ch < RIN_W / 4; ++ch) {
                const uint4 v = *(const uint4*)(row + ch * 4);
                agg2[ch*4+0] = __hfma2(w2, __builtin_bit_cast(__half2, v.x), agg2[ch*4+0]);
                agg2[ch*4+1] = __hfma2(w2, __builtin_bit_cast(__half2, v.y), agg2[ch*4+1]);
                agg2[ch*4+2] = __hfma2(w2, __builtin_bit_cast(__half2, v.z), agg2[ch*4+2]);
                agg2[ch*4+3] = __hfma2(w2, __builtin_bit_cast(__half2, v.w), agg2[ch*4+3]);
            }
        }
    }

    // unpack aggregate + own features to fp32
    float aggf[RIN_W * 2], hif[RIN_W * 2];
    const unsigned* me = h_in + tid * RIN_W;
#pragma unroll
    for (int p = 0; p < RIN_W; ++p) {
        const float2 fa = __half22float2(agg2[p]);
        const float2 fh = __half22float2(__builtin_bit_cast(__half2, me[p]));
        aggf[2*p] = fa.x; aggf[2*p+1] = fa.y;
        hif[2*p]  = fh.x; hif[2*p+1]  = fh.y;
    }

    float outv[COUT];
#pragma unroll
    for (int o = 0; o < COUT; ++o) {
        float acc = brel[o];
#pragma unroll
        for (int c = 0; c < CIN; ++c) {
            acc = fmaf(aggf[c], wrel[o * CIN + c], acc);
            acc = fmaf(hif[c],  wroot[o * CIN + c], acc);
        }
        outv[o] = fmaxf(acc, 0.f);
    }

    unsigned ow[ROUT_W];
#pragma unroll
    for (int p = 0; p < ROUT_W; ++p) {
        const float lo = (2*p     < COUT) ? outv[2*p]     : 0.f;
        const float hi = (2*p + 1 < COUT) ? outv[2*p + 1] : 0.f;
        ow[p] = __builtin_bit_cast(unsigned, __floats2half2_rn(lo, hi));
    }
    unsigned* orow = h_out + tid * ROUT_W;
    if constexpr (ROUT_W == 1) {
        orow[0] = ow[0];
    } else {
#pragma unroll
        for (int ch = 0; ch < ROUT_W / 4; ++ch)
            *(uint4*)(orow + ch * 4) =
                make_uint4(ow[ch*4], ow[ch*4+1], ow[ch*4+2], ow[ch*4+3]);
    }
}

__global__ __launch_bounds__(256) void conv_kernel(
    const float* __restrict__ x,
    const int*   __restrict__ eidx,   // [2, ETOT]
    const float* __restrict__ ew,     // [ETOT]
    const float* wr0, const float* br0, const float* wq0,
    const float* wr1, const float* br1, const float* wq1,
    const float* wr2, const float* br2, const float* wq2,
    const float* wr3, const float* br3, const float* wq3,
    const float* wr4, const float* br4, const float* wq4,
    float* __restrict__ HT)           // tile-transposed [NG/8][396][8]
{
    __shared__ unsigned s_edge[EPG];          // (half(w)<<16)|src
    __shared__ unsigned cnt[256];
    __shared__ unsigned pscan[256];
    __shared__ unsigned row_start[NPG + 1];
    __shared__ unsigned cursor[NPG];
    __shared__ __align__(16) unsigned bufA[NPG * 8];   // rows: 1 / 8 / 4 words
    __shared__ __align__(16) unsigned bufB[NPG * 12];  // rows: 12 / 8 / 1 words

    const int g     = blockIdx.x;
    const int tid   = threadIdx.x;
    const int ebase = g * EPG;
    const int nbase = g * NPG;

    // --- pass 1: per-destination counts (4 edges per thread-iter) ----------
    cnt[tid] = 0u;
    __syncthreads();
    const int4* dst4 = (const int4*)(eidx + ETOT + ebase);
    for (int q = tid; q < EPG / 4; q += 256) {
        const int4 d = dst4[q];
        atomicAdd(&cnt[d.x - nbase], 1u);
        atomicAdd(&cnt[d.y - nbase], 1u);
        atomicAdd(&cnt[d.z - nbase], 1u);
        atomicAdd(&cnt[d.w - nbase], 1u);
    }
    __syncthreads();

    // --- inclusive Hillis-Steele scan over 256 slots ------------------------
    pscan[tid] = cnt[tid];
    for (int st = 1; st < 256; st <<= 1) {
        __syncthreads();
        const unsigned v = (tid >= st) ? pscan[tid - st] : 0u;
        __syncthreads();
        pscan[tid] += v;
    }
    __syncthreads();
    if (tid < NPG) {
        const unsigned rs = pscan[tid] - cnt[tid];   // exclusive
        row_start[tid] = rs;
        cursor[tid]    = rs;
    }
    if (tid == 0) row_start[NPG] = EPG;
    __syncthreads();

    // --- pass 2: place edges sorted by destination, packed (w|src) ----------
    const int4*   src4 = (const int4*)(eidx + ebase);
    const float4* w4p  = (const float4*)(ew + ebase);
    for (int q = tid; q < EPG / 4; q += 256) {
        const int4   s = src4[q];
        const int4   d = dst4[q];
        const float4 w = w4p[q];
        {
            const unsigned slot = atomicAdd(&cursor[d.x - nbase], 1u);
            const __half hw = __float2half_rn(w.x);
            s_edge[slot] = ((unsigned)*(const unsigned short*)&hw << 16) | (unsigned)(s.x - nbase);
        }
        {
            const unsigned slot = atomicAdd(&cursor[d.y - nbase], 1u);
            const __half hw = __float2half_rn(w.y);
            s_edge[slot] = ((unsigned)*(const unsigned short*)&hw << 16) | (unsigned)(s.y - nbase);
        }
        {
            const unsigned slot = atomicAdd(&cursor[d.z - nbase], 1u);
            const __half hw = __float2half_rn(w.z);
            s_edge[slot] = ((unsigned)*(const unsigned short*)&hw << 16) | (unsigned)(s.z - nbase);
        }
        {
            const unsigned slot = atomicAdd(&cursor[d.w - nbase], 1u);
            const __half hw = __float2half_rn(w.w);
            s_edge[slot] = ((unsigned)*(const unsigned short*)&hw << 16) | (unsigned)(s.w - nbase);
        }
    }

    // --- pack x (198 x 2 fp32) into half2 rows (width 1) --------------------
    if (tid < NPG) {
        const float2 xv = ((const float2*)x)[nbase + tid];
        bufA[tid] = __builtin_bit_cast(unsigned, __floats2half2_rn(xv.x, xv.y));
    }
    __syncthreads();

    conv_layer_h<2, 20, 1, 12>(bufA, bufB, s_edge, row_start, wr0, br0, wq0, tid);
    __syncthreads();
    conv_layer_h<20, 15, 12, 8>(bufB, bufA, s_edge, row_start, wr1, br1, wq1, tid);
    __syncthreads();
    conv_layer_h<15, 10, 8, 8>(bufA, bufB, s_edge, row_start, wr2, br2, wq2, tid);
    __syncthreads();
    conv_layer_h<10, 5, 8, 4>(bufB, bufA, s_edge, row_start, wr3, br3, wq3, tid);
    __syncthreads();
    conv_layer_h<5, 2, 4, 1>(bufA, bufB, s_edge, row_start, wr4, br4, wq4, tid);
    __syncthreads();

    // --- store tile-transposed fp32: HT[g>>3][node*2+c][g&7] ----------------
    if (tid < NPG) {
        const float2 f = __half22float2(__builtin_bit_cast(__half2, bufB[tid]));
        float* ht = HT + (size_t)(g >> 3) * (396 * GPB);
        const int jj = g & 7;
        ht[(2 * tid)     * GPB + jj] = f.x;
        ht[(2 * tid + 1) * GPB + jj] = f.y;
    }
}

// ---------------------------------------------------------------------------
// MLP kernel: 8 graphs per block. Thread = output neuron, 8 accumulators.
// Inputs wave-uniform ([k][g] layout), weights lane-coalesced (WT[k][o]).
// ---------------------------------------------------------------------------
template <int K, int M>
__device__ __forceinline__ void mlpT(
    const float* __restrict__ inT,    // [K][8], uniform across lanes
    float* __restrict__ outT,         // [M][8]
    const float* __restrict__ wt,     // [K][M] transposed weights
    const float* __restrict__ bias,   // [M]
    int tid, bool relu)
{
    if (tid < M) {
        float acc[GPB];
        const float b = bias[tid];
#pragma unroll
        for (int j = 0; j < GPB; ++j) acc[j] = b;
#pragma unroll 4
        for (int k = 0; k < K; ++k) {
            const float wv = wt[k * M + tid];
            const float4 i0 = *(const float4*)(inT + k * GPB);
            const float4 i1 = *(const float4*)(inT + k * GPB + 4);
            acc[0] = fmaf(wv, i0.x, acc[0]);
            acc[1] = fmaf(wv, i0.y, acc[1]);
            acc[2] = fmaf(wv, i0.z, acc[2]);
            acc[3] = fmaf(wv, i0.w, acc[3]);
            acc[4] = fmaf(wv, i1.x, acc[4]);
            acc[5] = fmaf(wv, i1.y, acc[5]);
            acc[6] = fmaf(wv, i1.z, acc[6]);
            acc[7] = fmaf(wv, i1.w, acc[7]);
        }
#pragma unroll
        for (int j = 0; j < GPB; ++j)
            outT[tid * GPB + j] = relu ? fmaxf(acc[j], 0.f) : acc[j];
    }
}

__global__ __launch_bounds__(256) void mlp_kernel(
    const float* __restrict__ HT,     // [NG/8][396][8]
    const float* __restrict__ ws,     // workspace base (for WT*)
    const float* __restrict__ lb0, const float* __restrict__ lb1,
    const float* __restrict__ lb2, const float* __restrict__ lb3,
    const float* __restrict__ lb4,
    float* __restrict__ out)          // [NG, 2]
{
    __shared__ __align__(16) float bufA[200 * GPB];
    __shared__ __align__(16) float bufB[100 * GPB];

    const int tid = threadIdx.x;
    const float* __restrict__ ht = HT + (size_t)blockIdx.x * (396 * GPB);

    mlpT<396, 200>(ht,   bufA, ws + WT0_OFF, lb0, tid, true);
    __syncthreads();
    mlpT<200, 100>(bufA, bufB, ws + WT1_OFF, lb1, tid, true);
    __syncthreads();
    mlpT<100, 50>(bufB,  bufA, ws + WT2_OFF, lb2, tid, true);
    __syncthreads();
    mlpT<50, 10>(bufA,   bufB, ws + WT3_OFF, lb3, tid, true);
    __syncthreads();

    // layer 4 (10 -> 2) + softmax, one thread per graph
    if (tid < GPB) {
        const int j = tid;
        const float* __restrict__ wt4 = ws + WT4_OFF;
        float l0 = lb4[0], l1 = lb4[1];
#pragma unroll
        for (int k = 0; k < 10; ++k) {
            const float v = bufB[k * GPB + j];
            l0 = fmaf(v, wt4[k * 2 + 0], l0);
            l1 = fmaf(v, wt4[k * 2 + 1], l1);
        }
        const float m  = fmaxf(l0, l1);
        const float e0 = __expf(l0 - m), e1 = __expf(l1 - m);
        const float inv = 1.f / (e0 + e1);
        float2 p; p.x = e0 * inv; p.y = e1 * inv;
        ((float2*)out)[blockIdx.x * GPB + j] = p;
    }
}

extern "C" void kernel_launch(void* const* d_in, const int* in_sizes, int n_in,
                              void* d_out, int out_size, void* d_ws, size_t ws_size,
                              hipStream_t stream)
{
    const float* x    = (const float*)d_in[0];
    const int*   eidx = (const int*)  d_in[1];
    const float* ew   = (const float*)d_in[2];

    const float* wr[5]; const float* br[5]; const float* wq[5];
    for (int i = 0; i < 5; ++i) {
        wr[i] = (const float*)d_in[3 + 3 * i];
        br[i] = (const float*)d_in[4 + 3 * i];
        wq[i] = (const float*)d_in[5 + 3 * i];
    }
    const float* lw[5]; const float* lb[5];
    for (int i = 0; i < 5; ++i) {
        lw[i] = (const float*)d_in[18 + 2 * i];
        lb[i] = (const float*)d_in[19 + 2 * i];
    }

    float* ws = (float*)d_ws;

    wtrans_kernel<<<412, 256, 0, stream>>>(lw[0], lw[1], lw[2], lw[3], lw[4], ws);

    conv_kernel<<<NG, 256, 0, stream>>>(
        x, eidx, ew,
        wr[0], br[0], wq[0],
        wr[1], br[1], wq[1],
        wr[2], br[2], wq[2],
        wr[3], br[3], wq[3],
        wr[4], br[4], wq[4],
        ws /* HT at offset 0 */);

    mlp_kernel<<<NG / GPB, 256, 0, stream>>>(
        ws /* HT */, ws /* WT base */,
        lb[0], lb[1], lb[2], lb[3], lb[4],
        (float*)d_out);
}